// Round 8
// baseline (210.578 us; speedup 1.0000x reference)
//
#include <hip/hip_runtime.h>
#include <stdint.h>

#define B_   256
#define O_   128
#define D_   128
#define IN_  16384
#define NEGF (-9.0e15f)
#define TINYF 1.1754943508222875e-38f
#define WGSCOPE __HIP_MEMORY_SCOPE_WORKGROUP

// ---------------- threefry2x32 (JAX partitionable, 20 rounds) ----------------
__device__ __forceinline__ void tf2x32(uint32_t k0, uint32_t k1,
                                       uint32_t x0, uint32_t x1,
                                       uint32_t* o0, uint32_t* o1) {
  uint32_t k2 = k0 ^ k1 ^ 0x1BD11BDAu;
#define TFR(r) { x0 += x1; x1 = (x1 << (r)) | (x1 >> (32 - (r))); x1 ^= x0; }
  x0 += k0; x1 += k1;
  TFR(13) TFR(15) TFR(26) TFR(6)
  x0 += k1; x1 += k2 + 1u;
  TFR(17) TFR(29) TFR(16) TFR(24)
  x0 += k2; x1 += k0 + 2u;
  TFR(13) TFR(15) TFR(26) TFR(6)
  x0 += k0; x1 += k1 + 3u;
  TFR(17) TFR(29) TFR(16) TFR(24)
  x0 += k1; x1 += k2 + 4u;
  TFR(13) TFR(15) TFR(26) TFR(6)
  x0 += k2; x1 += k0 + 5u;
#undef TFR
  *o0 = x0; *o1 = x1;
}

__device__ __forceinline__ float gumbel_bits(uint32_t bits) {
  float f = __uint_as_float((bits >> 9) | 0x3f800000u) - 1.0f;  // [0,1)
  float u = fmaxf(TINYF, f + TINYF);
  return -logf(-logf(u));
}

__device__ __forceinline__ uint32_t mono32(float x) {
  int b = __float_as_int(x);
  return (uint32_t)b ^ ((uint32_t)(b >> 31) | 0x80000000u);
}

__device__ __forceinline__ float rl_f(float v, int l) {
  return __int_as_float(__builtin_amdgcn_readlane(__float_as_int(v), l));
}
__device__ __forceinline__ uint32_t rl_u(uint32_t v, int l) {
  return (uint32_t)__builtin_amdgcn_readlane((int)v, l);
}
__device__ __forceinline__ uint64_t rl_u64(uint64_t v, int l) {
  uint32_t lo = (uint32_t)__builtin_amdgcn_readlane((int)(uint32_t)v, l);
  uint32_t hi = (uint32_t)__builtin_amdgcn_readlane((int)(uint32_t)(v >> 32), l);
  return ((uint64_t)hi << 32) | lo;
}

// DPP reductions: xor1,2,4,8 butterfly + row_bcast15/31 funnel into lane 63.
// Bitwise-identical results to the round-5/6 passing trajectory.
#define DPPF(x, ctrl) __int_as_float(__builtin_amdgcn_mov_dpp( \
    __float_as_int(x), (ctrl), 0xf, 0xf, true))
#define DPPU(x, ctrl) ((uint32_t)__builtin_amdgcn_mov_dpp( \
    (int)(x), (ctrl), 0xf, 0xf, true))

__device__ __forceinline__ float wredmaxf(float x) {
  x = fmaxf(x, DPPF(x, 0xB1));
  x = fmaxf(x, DPPF(x, 0x4E));
  x = fmaxf(x, DPPF(x, 0x141));
  x = fmaxf(x, DPPF(x, 0x140));
  x = fmaxf(x, DPPF(x, 0x142));   // row_bcast15
  x = fmaxf(x, DPPF(x, 0x143));   // row_bcast31
  return rl_f(x, 63);
}
__device__ __forceinline__ float wredsumf(float x) {
  x = x + DPPF(x, 0xB1);
  x = x + DPPF(x, 0x4E);
  x = x + DPPF(x, 0x141);
  x = x + DPPF(x, 0x140);
  x = x + DPPF(x, 0x142);
  x = x + DPPF(x, 0x143);
  return rl_f(x, 63);
}
__device__ __forceinline__ uint32_t wredmaxu(uint32_t x) {
  uint32_t y;
  y = DPPU(x, 0xB1);  x = x > y ? x : y;
  y = DPPU(x, 0x4E);  x = x > y ? x : y;
  y = DPPU(x, 0x141); x = x > y ? x : y;
  y = DPPU(x, 0x140); x = x > y ? x : y;
  y = DPPU(x, 0x142); x = x > y ? x : y;
  y = DPPU(x, 0x143); x = x > y ? x : y;
  return rl_u(x, 63);
}

// ---------------- Kernel A: M[b][p][o] = <enc[b,p,:], W[o, p*D:(p+1)*D]> ----
__global__ __launch_bounds__(256, 1) void build_M(
    const float* __restrict__ enc, const float* __restrict__ W,
    float* __restrict__ M) {
  const int p  = blockIdx.x;
  const int b0 = blockIdx.y * 128;
  const int t  = threadIdx.x;

  __shared__ float Ws[128 * 132];
  __shared__ float Es[128 * 132];

  {
    const int rgrp = t >> 5;      // 8 rows per iteration
    const int c16  = t & 31;      // float4 index within a 512B row
#pragma unroll
    for (int k = 0; k < 16; k++) {
      int row = k * 8 + rgrp;
      *(float4*)(Ws + row * 132 + c16 * 4) =
          *(const float4*)(W + (size_t)row * IN_ + p * D_ + c16 * 4);
    }
#pragma unroll
    for (int k = 0; k < 16; k++) {
      int row = k * 8 + rgrp;
      *(float4*)(Es + row * 132 + c16 * 4) =
          *(const float4*)(enc + ((size_t)(b0 + row) * O_ + p) * D_ + c16 * 4);
    }
  }
  __syncthreads();

  const int og = t & 15, bg = t >> 4;
  float acc0[8][8] = {}, acc1[8][8] = {};

  for (int dc = 0; dc < 128; dc += 4) {
    float4 wv[8], ev[8];
#pragma unroll
    for (int oi = 0; oi < 8; oi++)
      wv[oi] = *(const float4*)(Ws + (og + 16 * oi) * 132 + dc);
#pragma unroll
    for (int bi = 0; bi < 8; bi++)
      ev[bi] = *(const float4*)(Es + (bg + 16 * bi) * 132 + dc);
#pragma unroll
    for (int bi = 0; bi < 8; bi++)
#pragma unroll
      for (int oi = 0; oi < 8; oi++) {
        acc0[bi][oi] += ev[bi].x * wv[oi].x;
        acc1[bi][oi] += ev[bi].y * wv[oi].y;
        acc0[bi][oi] += ev[bi].z * wv[oi].z;
        acc1[bi][oi] += ev[bi].w * wv[oi].w;
      }
  }
#pragma unroll
  for (int bi = 0; bi < 8; bi++) {
    int b = b0 + bg + 16 * bi;
#pragma unroll
    for (int oi = 0; oi < 8; oi++) {
      int o = og + 16 * oi;
      M[((size_t)b * O_ + p) * O_ + o] = acc0[bi][oi] + acc1[bi][oi];
    }
  }
}

// ---------------- Kernel S: fused sampler -----------------------------------
// 512 threads. wave0 = serial sampler. waves1-3 = gumbel producers (sprint all
// 128 rows, then exit). waves4-7 = rank/err workers on 8-step LDS snapshots.
__global__ __launch_bounds__(512, 1) void sampler(
    const float* __restrict__ M, const float* __restrict__ bias,
    const float* __restrict__ enc, const float* __restrict__ W, int use_M,
    float* __restrict__ out_pos, float* __restrict__ out_ls,
    float* __restrict__ out_err) {
  const int b = blockIdx.x;
  const int t = threadIdx.x;
  const int lane = t & 63;
  const int w = t >> 6;

  __shared__ float  Mlds[O_ * O_];          // 64 KB
  __shared__ float  Glds[O_ * O_];          // 64 KB (all 128 gumbel rows)
  __shared__ double snapPd[16 * 64 * 2];    // 16 KB
  __shared__ unsigned long long snapMk[16 * 2];
  __shared__ int posb[O_];
  __shared__ int flags[O_];
  __shared__ int doneStep, errTot, chunksDone;

  if (use_M) {
    const float4* src = (const float4*)(M + (size_t)b * O_ * O_);
    for (int i = t; i < O_ * O_ / 4; i += 512) ((float4*)Mlds)[i] = src[i];
  } else {
    for (int idx = t; idx < O_ * O_; idx += 512) {
      int p = idx >> 7, o = idx & 127;
      const float* er = enc + ((size_t)b * O_ + p) * D_;
      const float* wr = W + (size_t)o * IN_ + p * D_;
      float s = 0.f;
      for (int d = 0; d < D_; d += 4) {
        float4 e4 = *(const float4*)(er + d);
        float4 w4 = *(const float4*)(wr + d);
        s += e4.x * w4.x + e4.y * w4.y + e4.z * w4.z + e4.w * w4.w;
      }
      Mlds[idx] = s;
    }
  }
  if (t < O_) flags[t] = 0;
  if (t == 0) { doneStep = 0; errTot = 0; chunksDone = 0; }
  __syncthreads();

  if (w >= 1 && w <= 3) {
    // ---- producers: sprint all rows r == (w-1) mod 3, then exit ----
    for (int r = w - 1; r < O_; r += 3) {
      uint32_t k0j, k1j, w0, w1;
      tf2x32(0u, 42u, 0u, (uint32_t)r, &k0j, &k1j);
      uint32_t m1 = (uint32_t)(b * O_ + lane);
      tf2x32(k0j, k1j, 0u, m1, &w0, &w1);
      float g1 = gumbel_bits(w0 ^ w1);
      tf2x32(k0j, k1j, 0u, m1 + 64u, &w0, &w1);
      float g2 = gumbel_bits(w0 ^ w1);
      Glds[r * O_ + lane] = g1;
      Glds[r * O_ + 64 + lane] = g2;
      if (lane == 0)
        __hip_atomic_store(&flags[r], 1, __ATOMIC_RELEASE, WGSCOPE);
    }
    return;
  }

  if (w == 0) {
    // ---- consumer: the serial decision chain ----
    __builtin_amdgcn_s_setprio(3);
#define WAITF(r) { int _n = 0; \
    while (__hip_atomic_load(&flags[r], __ATOMIC_ACQUIRE, WGSCOPE) == 0 && \
           _n < (1 << 26)) { _n++; __builtin_amdgcn_s_sleep(1); } }
    double Pd1 = 0.0, Pd2 = 0.0;
    for (int p = 0; p < O_; p++) {
      Pd1 += (double)Mlds[p * O_ + lane];
      Pd2 += (double)Mlds[p * O_ + 64 + lane];
    }
    const float b1f = bias[lane], b2f = bias[lane + 64];
    int mk1 = 0, mk2 = 0;
    unsigned long long bmk1 = 0ull, bmk2 = 0ull;
    double ls_sum = 0.0;

    WAITF(7); WAITF(8); WAITF(9);    // 3 in-order producers => rows 0..9 ready
    float g1c = Glds[lane],      g2c = Glds[64 + lane];
    float g1n = Glds[O_ + lane], g2n = Glds[O_ + 64 + lane];

    for (int j = 0; j < O_; j++) {
      if ((j & 7) == 0) {
        if (j) {  // 3 consecutive flags => all rows <= j+9 produced
          int rA = j + 7, rB = j + 8, rC = j + 9;
          if (rC > 127) { rA = 125; rB = 126; rC = 127; }
          WAITF(rA); WAITF(rB); WAITF(rC);
        }
        int c = j >> 3;   // snapshot state entering step 8c
        double2 pv; pv.x = Pd1; pv.y = Pd2;
        *(double2*)&snapPd[(c * 64 + lane) * 2] = pv;
        if (lane == 0) { snapMk[c * 2] = bmk1; snapMk[c * 2 + 1] = bmk2; }
      }
      // exact reference op order (bit-identical to round-5/6/7 trajectory)
      float pm1 = mk1 ? NEGF : ((float)Pd1 + b1f);
      float pm2 = mk2 ? NEGF : ((float)Pd2 + b2f);
      float mx = wredmaxf(fmaxf(pm1, pm2));
      float s1 = pm1 - mx, s2 = pm2 - mx;
      float ss = wredsumf(expf(s1) + expf(s2));
      float lse = logf(ss);
      float lp1 = s1 - lse, lp2 = s2 - lse;
      float y1 = lp1 + g1c, y2 = lp2 + g2c;
      uint32_t u1 = mono32(y1), u2 = mono32(y2);
      uint32_t um = wredmaxu(u1 > u2 ? u1 : u2);
      unsigned long long bal1 = __ballot(u1 == um);
      unsigned long long bal2 = __ballot(u2 == um);
      int pos = bal1 ? (__ffsll(bal1) - 1) : (64 + __ffsll(bal2) - 1);

      float lsel = rl_f((pos < 64) ? lp1 : lp2, pos & 63);
      ls_sum += (double)lsel;

      if (lane == 0) {
        posb[j] = pos;
        out_pos[(size_t)b * O_ + (O_ - 1 - j)] = (float)pos;
      }
      mk1 |= (lane == pos);
      mk2 |= (lane + 64 == pos);
      if (pos < 64) bmk1 |= 1ull << pos; else bmk2 |= 1ull << (pos - 64);
      Pd1 -= (double)Mlds[pos * O_ + lane];
      Pd2 -= (double)Mlds[pos * O_ + 64 + lane];
      if ((j & 7) == 7 && lane == 0)   // publish once per chunk (no per-step flush)
        __hip_atomic_store(&doneStep, j + 1, __ATOMIC_RELEASE, WGSCOPE);

      g1c = g1n; g2c = g2n;
      int r = j + 2;
      if (r < O_) {
        g1n = Glds[r * O_ + lane];
        g2n = Glds[r * O_ + 64 + lane];
      }
    }
#undef WAITF
    if (lane == 0) out_ls[b] = (float)ls_sum;
    return;
  }

  // ---- rank/err workers: waves 4-7, chunk c == (w-4) mod 4 ----
  {
    const float b1f = bias[lane], b2f = bias[lane + 64];
    for (int c = w - 4; c < 16; c += 4) {
      int need = 8 * c + 8, n = 0;
      while (__hip_atomic_load(&doneStep, __ATOMIC_ACQUIRE, WGSCOPE) < need &&
             n < (1 << 26)) { n++; __builtin_amdgcn_s_sleep(8); }
      double2 pv = *(double2*)&snapPd[(c * 64 + lane) * 2];
      double Pd1 = pv.x, Pd2 = pv.y;
      unsigned long long bmk1 = snapMk[c * 2], bmk2 = snapMk[c * 2 + 1];
      int err_acc = 0;
      for (int j = 8 * c; j < 8 * c + 8; j++) {
        float p1 = (float)Pd1 + b1f;   // bit-identical to sampler's score
        float p2 = (float)Pd2 + b2f;
        uint64_t K1 = ((uint64_t)mono32(p1) << 7) | (uint32_t)(127 - lane);
        uint64_t K2 = ((uint64_t)mono32(p2) << 7) | (uint32_t)(63 - lane);
        int c1 = 0, c2 = 0;
#pragma unroll 8
        for (int q = 0; q < 64; q++) {
          uint64_t s1v = rl_u64(K1, q), s2v = rl_u64(K2, q);
          c1 += (s1v > K1) ? 1 : 0;
          c1 += (s2v > K1) ? 1 : 0;
          c2 += (s1v > K2) ? 1 : 0;
          c2 += (s2v > K2) ? 1 : 0;
        }
        unsigned long long t1 = __ballot(c1 == j), t2 = __ballot(c2 == j);
        int topl, msk;
        if (t1) { topl = __ffsll(t1) - 1; msk = (int)((bmk1 >> topl) & 1); }
        else    { topl = __ffsll(t2) - 1; msk = (int)((bmk2 >> topl) & 1); }
        err_acc += msk;

        int pos = posb[j];
        if (pos < 64) bmk1 |= 1ull << pos; else bmk2 |= 1ull << (pos - 64);
        Pd1 -= (double)Mlds[pos * O_ + lane];
        Pd2 -= (double)Mlds[pos * O_ + 64 + lane];
      }
      if (lane == 0) {
        __hip_atomic_fetch_add(&errTot, err_acc, __ATOMIC_RELAXED, WGSCOPE);
        int prev = __hip_atomic_fetch_add(&chunksDone, 1, __ATOMIC_ACQ_REL,
                                          WGSCOPE);
        if (prev == 15)
          out_err[b] = (float)__hip_atomic_load(&errTot, __ATOMIC_ACQUIRE,
                                                WGSCOPE);
      }
    }
  }
}

extern "C" void kernel_launch(void* const* d_in, const int* in_sizes, int n_in,
                              void* d_out, int out_size, void* d_ws, size_t ws_size,
                              hipStream_t stream) {
  const float* enc  = (const float*)d_in[0];
  const float* W    = (const float*)d_in[1];
  const float* bias = (const float*)d_in[2];
  float* out     = (float*)d_out;
  float* out_pos = out;                  // [256][128] positions (as f32)
  float* out_ls  = out + B_ * O_;        // [256]
  float* out_err = out + B_ * O_ + B_;   // [256]

  float* M = (float*)d_ws;
  const size_t needM = (size_t)B_ * O_ * O_ * sizeof(float);  // 16.7 MB
  int use_M = (ws_size >= needM) ? 1 : 0;

  if (use_M) build_M<<<dim3(O_, 2), 256, 0, stream>>>(enc, W, M);
  sampler<<<dim3(B_), 512, 0, stream>>>(M, bias, enc, W, use_M,
                                        out_pos, out_ls, out_err);
}